// Round 15
// baseline (285.732 us; speedup 1.0000x reference)
//
#include <hip/hip_runtime.h>
#include <hip/hip_bf16.h>
#include <hip/hip_fp16.h>
#include <math.h>

// SGC: out = log_softmax( S^2 X W^T + b ), S = D^-1/2 (A+I) D^-1/2
// t0 = dis .* (X W^T) in *f16* (pre-scaled 80 B rows).
// Props (r13/r15): merged hops with QUARTER-phase gather order. r14 counters
// showed the 4 MB half-window still thrashes (FETCH 97 MB vs 22 compulsory:
// a cache-sized working set has zero slack vs streams + associativity).
// Quarter windows (2 MB, 2x slack) via a 1024-key sort in p4
// (dstLocal*4 + srcQuarter) and three per-node boundaries mid1/2/3.
// Gather: 5-lane group per dst, 12 nodes/wave, f32 accum, 8 edges in flight.
// r10 lesson: NO nontemporal on re-read data; only fin final store NT.
// CSR build: r7 LDS counting sort + r14's 512-thread blocks (p3a off the
// critical top-5); r11 folds (is64 in p3a, p2 scan in p4). 6 dispatches.

#define N_NODES 100000
#define N_FEAT  128
#define N_CLASS 40

#define RANGE   256           // dsts per fine bucket (pow2: dst>>8)
#define NBALLOC 512
#define NBUSED  391           // ceil(100000/256)
#define CAP     8704          // fine bucket cap (mean 8192 + ~5.7 sigma)
#define P3BLK   6250          // edges per p3a block (grid = ceil(E/P3BLK))
#define P3THR   512           // p3a threads per block (r14, proven)
#define Q1      25000         // quarter boundaries (2 MB table windows)
#define Q2      50000
#define Q3      75000

typedef __attribute__((ext_vector_type(8))) short short8;   // 8 bf16 (4 VGPRs)
typedef __attribute__((ext_vector_type(4))) float floatx4;  // f32x4 (NT-able)

__device__ __forceinline__ int edge_word(const int* ei, int elem, int is64) {
    return is64 ? ei[2 * elem] : ei[elem];
}
__device__ __forceinline__ int quarter_of(int src) {
    return (src >= Q1) + (src >= Q2) + (src >= Q3);
}

// P3a: per-block is64 detect, block-local LDS counting sort over 512 fine
// buckets, coalesced bucket-grouped run writes into tmp[f*CAP + p].
// bucketCount (pre-zeroed by memset) accumulates global per-bucket totals.
__global__ __launch_bounds__(P3THR) void p3a_scatter(
    const int* __restrict__ ei, int E,
    int* __restrict__ bucketCount, unsigned int* __restrict__ tmp)
{
    __shared__ unsigned int srt[P3BLK];     // bucket-grouped records
    __shared__ unsigned short fb[P3BLK];    // bucket id per record
    __shared__ int hist[NBALLOC];
    __shared__ int lbase[NBALLOC];          // block-local exclusive scan
    __shared__ int gbase[NBALLOC];          // global run base per bucket
    __shared__ int cur[NBALLOC];
    __shared__ int sc[NBALLOC];
    __shared__ int s_is64;
    int t = threadIdx.x;
    if (t < NBALLOC) hist[t] = 0;
    if (t < 64) {                            // wave 0: int32/int64 detect
        int nz = (ei[2 * t + 1] != 0) ? 1 : 0;
        unsigned long long bl = __ballot(nz);
        if (t == 0) s_is64 = (bl == 0ull) ? 1 : 0;
    }
    __syncthreads();
    int is64 = s_is64;
    int per = (E + gridDim.x - 1) / gridDim.x;
    int e0 = blockIdx.x * per;
    int e1 = min(E, e0 + per);
    int n = e1 - e0;
    for (int e = e0 + t; e < e1; e += P3THR) {
        int c = edge_word(ei, E + e, is64);
        atomicAdd(&hist[c >> 8], 1);
    }
    __syncthreads();
    int hv = hist[t];
    sc[t] = hv;
    __syncthreads();
    for (int o = 1; o < NBALLOC; o <<= 1) {
        int y = (t >= o) ? sc[t - o] : 0;
        __syncthreads();
        sc[t] += y;
        __syncthreads();
    }
    int excl = sc[t] - hv;
    lbase[t] = excl;
    cur[t] = excl;
    gbase[t] = hv ? atomicAdd(&bucketCount[t], hv) : 0;
    __syncthreads();
    for (int e = e0 + t; e < e1; e += P3THR) {
        int c = edge_word(ei, E + e, is64);
        int r = edge_word(ei, e, is64);
        int f = c >> 8;
        int p = atomicAdd(&cur[f], 1);
        srt[p] = ((unsigned)(c & 255) << 24) | (unsigned)r;
        fb[p] = (unsigned short)f;
    }
    __syncthreads();
    for (int i = t; i < n; i += P3THR) {
        int f = fb[i];
        int p = gbase[f] + (i - lbase[f]);
        if (p < CAP) tmp[(size_t)f * CAP + p] = srt[i];
    }
}

// P4: folded p2 scan of bucketCount -> block base; then per-fine-bucket LDS
// counting sort with 1024 keys (dlf*4 + srcQuarter) -> starts, mid1/2/3,
// dis, srcsB (byte offsets, src*80, coalesced). tmp[b*CAP + i] records.
__global__ __launch_bounds__(256) void p4_sort(
    const unsigned int* __restrict__ tmp, const int* __restrict__ bucketCount,
    int* __restrict__ starts, int* __restrict__ mid1, int* __restrict__ mid2,
    int* __restrict__ mid3, float* __restrict__ dis,
    int* __restrict__ srcsB, int N, int E)
{
    __shared__ int srt[CAP];
    __shared__ int hist[1024];
    __shared__ int sc[256];
    __shared__ int cur[1024];
    __shared__ int cnt[NBALLOC];
    __shared__ int base_s;
    int b = blockIdx.x, t = threadIdx.x;
    int g0 = b * RANGE;
    int gcnt = N - g0;
    if (gcnt > RANGE) gcnt = RANGE;
    // --- folded p2: scan the 512 global bucket counts for this block's base
    for (int i = t; i < NBALLOC; i += 256) cnt[i] = bucketCount[i];
    __syncthreads();
    int p0 = cnt[2 * t], p1 = cnt[2 * t + 1];
    sc[t] = p0 + p1;
    __syncthreads();
    for (int o = 1; o < 256; o <<= 1) {
        int y = (t >= o) ? sc[t - o] : 0;
        __syncthreads();
        sc[t] += y;
        __syncthreads();
    }
    if (t == 0) {
        int pairs = b >> 1;
        int base = (pairs > 0) ? sc[pairs - 1] : 0;
        if (b & 1) base += cnt[b - 1];
        base_s = base;
        if (b == 0) starts[N_NODES] = E;
    }
    __syncthreads();
    int base = base_s;
    int n = cnt[b];
    int nr = min(n, CAP);                       // records actually present
    const unsigned int* rec = tmp + (size_t)b * CAP;
    hist[t] = 0; hist[t + 256] = 0; hist[t + 512] = 0; hist[t + 768] = 0;
    __syncthreads();
    for (int i = t; i < nr; i += 256) {
        unsigned v = rec[i];
        int key = (int)((v >> 24) << 2) | quarter_of((int)(v & 0xFFFFFFu));
        atomicAdd(&hist[key], 1);
    }
    __syncthreads();
    int c0 = hist[4 * t], c1 = hist[4 * t + 1];
    int c2 = hist[4 * t + 2], c3 = hist[4 * t + 3];
    int tot = c0 + c1 + c2 + c3;
    sc[t] = tot;
    __syncthreads();
    for (int o = 1; o < 256; o <<= 1) {
        int y = (t >= o) ? sc[t - o] : 0;
        __syncthreads();
        sc[t] += y;
        __syncthreads();
    }
    int excl = sc[t] - tot;
    if (t < gcnt) {
        starts[g0 + t] = base + excl;
        mid1[g0 + t] = base + excl + c0;
        mid2[g0 + t] = base + excl + c0 + c1;
        mid3[g0 + t] = base + excl + c0 + c1 + c2;
        dis[g0 + t] = rsqrtf((float)(tot + 1));   // +1 self-loop
    }
    cur[4 * t] = excl;
    cur[4 * t + 1] = excl + c0;
    cur[4 * t + 2] = excl + c0 + c1;
    cur[4 * t + 3] = excl + c0 + c1 + c2;
    __syncthreads();
    for (int i = t; i < nr; i += 256) {
        unsigned v = rec[i];
        int src = (int)(v & 0xFFFFFFu);
        int key = (int)((v >> 24) << 2) | quarter_of(src);
        int p = atomicAdd(&cur[key], 1);
        srt[p] = src * 80;                       // pre-scaled byte offset
    }
    __syncthreads();
    for (int i = t; i < nr; i += 256) srcsB[base + i] = srt[i];
}

// ---------------------------------------------------------------------------
__device__ __forceinline__ unsigned short f2bf(float f) {   // RTN f32 -> bf16
    unsigned u = __float_as_uint(f);
    unsigned r = u + 0x7FFFu + ((u >> 16) & 1u);
    return (unsigned short)(r >> 16);
}
__device__ __forceinline__ __half2 u2h(unsigned w) {
    union { unsigned u; __half2 h; } c; c.u = w; return c.h;
}
__device__ __forceinline__ unsigned h2u(__half2 h) {
    union { unsigned u; __half2 h; } c; c.h = h; return c.u;
}

// t0 = dis .* (X @ W^T), f16, row stride 40 (80 B). One wave per 16 nodes.
// MFMA on bf16 inputs (f32 accumulate), output stored f16.
__global__ __launch_bounds__(256) void transform_mfma(
    const float* __restrict__ x, const float* __restrict__ W,
    const float* __restrict__ dis, unsigned short* __restrict__ t0, int N)
{
    __shared__ uint4 Wl[3 * 4 * 64];        // B frags, bf16-packed: 12 KiB
    int t = threadIdx.x;
    for (int i = t; i < 3 * 4 * 64; i += 256) {
        int lane = i & 63;
        int kc = (i >> 6) & 3;
        int nt = i >> 8;
        int n = nt * 16 + (lane & 15);
        int k = kc * 32 + (lane >> 4) * 8;
        union { unsigned short s[8]; uint4 v; } u;
        #pragma unroll
        for (int j = 0; j < 8; ++j)
            u.s[j] = (n < N_CLASS) ? f2bf(W[n * N_FEAT + k + j]) : (unsigned short)0;
        Wl[i] = u.v;
    }
    __syncthreads();
    int wave = (blockIdx.x * blockDim.x + threadIdx.x) >> 6;
    int lane = threadIdx.x & 63;
    int ntile = (N + 15) / 16;
    if (wave >= ntile) return;
    int m = lane & 15, quad = lane >> 4;
    int row = wave * 16 + m;
    const short8* Wf = reinterpret_cast<const short8*>(Wl);
    floatx4 acc0 = {0.f, 0.f, 0.f, 0.f}, acc1 = acc0, acc2 = acc0;
    #pragma unroll
    for (int kc = 0; kc < 4; ++kc) {
        const float4* xr = reinterpret_cast<const float4*>(
            x + (size_t)row * N_FEAT + kc * 32 + quad * 8);
        float4 a0 = xr[0], a1 = xr[1];
        short8 af;
        af[0] = f2bf(a0.x); af[1] = f2bf(a0.y); af[2] = f2bf(a0.z); af[3] = f2bf(a0.w);
        af[4] = f2bf(a1.x); af[5] = f2bf(a1.y); af[6] = f2bf(a1.z); af[7] = f2bf(a1.w);
        short8 b0 = Wf[(0 * 4 + kc) * 64 + lane];
        short8 b1 = Wf[(1 * 4 + kc) * 64 + lane];
        short8 b2 = Wf[(2 * 4 + kc) * 64 + lane];
        acc0 = __builtin_amdgcn_mfma_f32_16x16x32_bf16(af, b0, acc0, 0, 0, 0);
        acc1 = __builtin_amdgcn_mfma_f32_16x16x32_bf16(af, b1, acc1, 0, 0, 0);
        acc2 = __builtin_amdgcn_mfma_f32_16x16x32_bf16(af, b2, acc2, 0, 0, 0);
    }
    #pragma unroll
    for (int r = 0; r < 4; ++r) {
        int rw = wave * 16 + quad * 4 + r;
        float ds = dis[rw];
        unsigned short* tr = t0 + (size_t)rw * N_CLASS;
        tr[m] = __half_as_ushort(__float2half(ds * acc0[r]));
        tr[16 + m] = __half_as_ushort(__float2half(ds * acc1[r]));
        if (m < 8) tr[32 + m] = __half_as_ushort(__float2half(ds * acc2[r]));
    }
}

// ---------------------------------------------------------------------------
// Group-per-node gather: 12 groups x 5 lanes per wave; lane sl owns bytes
// [16*sl, 16*sl+16) of the 80 B row. f32 accumulation in two banks.
struct F8 { float v0, v1, v2, v3, v4, v5, v6, v7; };

__device__ __forceinline__ void acc8(F8& a, uint4 r) {
    float2 f0 = __half22float2(u2h(r.x));
    float2 f1 = __half22float2(u2h(r.y));
    float2 f2 = __half22float2(u2h(r.z));
    float2 f3 = __half22float2(u2h(r.w));
    a.v0 += f0.x; a.v1 += f0.y; a.v2 += f1.x; a.v3 += f1.y;
    a.v4 += f2.x; a.v5 += f2.y; a.v6 += f3.x; a.v7 += f3.y;
}

// Gather one edge range [e0, e1): 8 edges in flight, A/B bank alternation.
__device__ __forceinline__ void gather_range(
    const char* tbs, const int* __restrict__ srcsB, int e0, int e1,
    F8& A, F8& B)
{
    int e = e0;
    int ea = min(e1, (e0 + 3) & ~3);
    for (; e < ea; ++e) {                       // align to 16 B
        unsigned o = (unsigned)srcsB[e];
        uint4 r = *reinterpret_cast<const uint4*>(tbs + o);
        acc8(A, r);
    }
    for (; e + 8 <= e1; e += 8) {               // 8 gathers in flight
        int4 oa = *reinterpret_cast<const int4*>(srcsB + e);
        int4 ob = *reinterpret_cast<const int4*>(srcsB + e + 4);
        uint4 r0 = *reinterpret_cast<const uint4*>(tbs + (unsigned)oa.x);
        uint4 r1 = *reinterpret_cast<const uint4*>(tbs + (unsigned)oa.y);
        uint4 r2 = *reinterpret_cast<const uint4*>(tbs + (unsigned)oa.z);
        uint4 r3 = *reinterpret_cast<const uint4*>(tbs + (unsigned)oa.w);
        uint4 r4 = *reinterpret_cast<const uint4*>(tbs + (unsigned)ob.x);
        uint4 r5 = *reinterpret_cast<const uint4*>(tbs + (unsigned)ob.y);
        uint4 r6 = *reinterpret_cast<const uint4*>(tbs + (unsigned)ob.z);
        uint4 r7 = *reinterpret_cast<const uint4*>(tbs + (unsigned)ob.w);
        acc8(A, r0); acc8(B, r1); acc8(A, r2); acc8(B, r3);
        acc8(A, r4); acc8(B, r5); acc8(A, r6); acc8(B, r7);
    }
    for (; e + 4 <= e1; e += 4) {               // 4-wide remainder
        int4 o4 = *reinterpret_cast<const int4*>(srcsB + e);
        uint4 r0 = *reinterpret_cast<const uint4*>(tbs + (unsigned)o4.x);
        uint4 r1 = *reinterpret_cast<const uint4*>(tbs + (unsigned)o4.y);
        uint4 r2 = *reinterpret_cast<const uint4*>(tbs + (unsigned)o4.z);
        uint4 r3 = *reinterpret_cast<const uint4*>(tbs + (unsigned)o4.w);
        acc8(A, r0); acc8(B, r1); acc8(A, r2); acc8(B, r3);
    }
    for (; e < e1; ++e) {                       // tail <= 3 edges
        unsigned o = (unsigned)srcsB[e];
        uint4 r = *reinterpret_cast<const uint4*>(tbs + o);
        acc8(A, r);
    }
}

// Shared prologue + merged four-quarter gather. Self term is added in the
// quarter containing d (keeps table accesses inside the hot 2 MB window).
#define GATHER_Q(tin)                                                          \
    int wv = (blockIdx.x * blockDim.x + threadIdx.x) >> 6;                     \
    int lane = threadIdx.x & 63;                                               \
    int g = lane / 5;                                                          \
    int sl = lane - g * 5;                                                     \
    if (g > 11) { g = 11; sl = 0; }                                            \
    int d = wv * 12 + g;                                                       \
    int act = (lane < 60) && (d < N);                                          \
    int dc = min(d, N - 1);                                                    \
    int e0 = starts[dc];                                                       \
    int m1 = mid1[dc];                                                         \
    int m2 = mid2[dc];                                                         \
    int m3 = mid3[dc];                                                         \
    int e1 = starts[dc + 1];                                                   \
    if (d >= N) { m1 = e0; m2 = e0; m3 = e0; e1 = e0; }                        \
    int slo = sl << 4;                                                         \
    const char* tbs = (const char*)(tin) + slo;                                \
    int sq = quarter_of(dc);                                                   \
    F8 A = {0,0,0,0,0,0,0,0}, B = {0,0,0,0,0,0,0,0};                           \
    if (sq == 0) { uint4 rs = *reinterpret_cast<const uint4*>(tbs + (size_t)dc * 80); acc8(A, rs); } \
    gather_range(tbs, srcsB, e0, m1, A, B);     /* quarter 0 */                \
    if (sq == 1) { uint4 rs = *reinterpret_cast<const uint4*>(tbs + (size_t)dc * 80); acc8(A, rs); } \
    gather_range(tbs, srcsB, m1, m2, A, B);     /* quarter 1 */                \
    if (sq == 2) { uint4 rs = *reinterpret_cast<const uint4*>(tbs + (size_t)dc * 80); acc8(A, rs); } \
    gather_range(tbs, srcsB, m2, m3, A, B);     /* quarter 2 */                \
    if (sq == 3) { uint4 rs = *reinterpret_cast<const uint4*>(tbs + (size_t)dc * 80); acc8(A, rs); } \
    gather_range(tbs, srcsB, m3, e1, A, B);     /* quarter 3 */                \
    A.v0 += B.v0; A.v1 += B.v1; A.v2 += B.v2; A.v3 += B.v3;                    \
    A.v4 += B.v4; A.v5 += B.v5; A.v6 += B.v6; A.v7 += B.v7;

// Middle hop (merged quarters): tout[d] = f16( dd^2 * (t[d] + sum t[src]) ).
__global__ __launch_bounds__(256) void prop_hop(
    const unsigned short* __restrict__ tin, unsigned short* __restrict__ tout,
    const int* __restrict__ starts, const int* __restrict__ mid1,
    const int* __restrict__ mid2, const int* __restrict__ mid3,
    const int* __restrict__ srcsB, const float* __restrict__ dis, int N)
{
    GATHER_Q(tin)
    if (act) {
        float dd = dis[dc];
        float sc = dd * dd;
        uint4 o;
        o.x = h2u(__floats2half2_rn(sc * A.v0, sc * A.v1));
        o.y = h2u(__floats2half2_rn(sc * A.v2, sc * A.v3));
        o.z = h2u(__floats2half2_rn(sc * A.v4, sc * A.v5));
        o.w = h2u(__floats2half2_rn(sc * A.v6, sc * A.v7));
        *reinterpret_cast<uint4*>((char*)tout + (size_t)d * 80 + slo) = o;
    }
}

// Final hop (merged quarters) fused with bias + log_softmax. Softmax reduce
// = 4 rotate-shfls within the 5-lane group. Final stores NT (never re-read).
__global__ __launch_bounds__(256) void prop_fin(
    const unsigned short* __restrict__ tin, float* __restrict__ out,
    const int* __restrict__ starts, const int* __restrict__ mid1,
    const int* __restrict__ mid2, const int* __restrict__ mid3,
    const int* __restrict__ srcsB, const float* __restrict__ dis,
    const float* __restrict__ bias, int N)
{
    GATHER_Q(tin)
    float dd = dis[dc];
    float4 blo = reinterpret_cast<const float4*>(bias)[sl * 2];       // sl<5
    float4 bhi = reinterpret_cast<const float4*>(bias)[sl * 2 + 1];
    float v0 = dd * A.v0 + blo.x, v1 = dd * A.v1 + blo.y;
    float v2 = dd * A.v2 + blo.z, v3 = dd * A.v3 + blo.w;
    float v4 = dd * A.v4 + bhi.x, v5 = dd * A.v5 + bhi.y;
    float v6 = dd * A.v6 + bhi.z, v7 = dd * A.v7 + bhi.w;
    float mx = fmaxf(fmaxf(fmaxf(v0, v1), fmaxf(v2, v3)),
                     fmaxf(fmaxf(v4, v5), fmaxf(v6, v7)));
    int rot = g * 5 + ((sl + 1 == 5) ? 0 : sl + 1);     // next lane in group
    float tmx = mx;
    #pragma unroll
    for (int k = 0; k < 4; ++k) { tmx = __shfl(tmx, rot); mx = fmaxf(mx, tmx); }
    float s = expf(v0 - mx) + expf(v1 - mx) + expf(v2 - mx) + expf(v3 - mx)
            + expf(v4 - mx) + expf(v5 - mx) + expf(v6 - mx) + expf(v7 - mx);
    float ts = s;
    #pragma unroll
    for (int k = 0; k < 4; ++k) { ts = __shfl(ts, rot); s += ts; }
    if (act) {
        float ls = mx + logf(s);
        float* ro = out + (size_t)d * N_CLASS + sl * 8;
        floatx4 lo = {v0 - ls, v1 - ls, v2 - ls, v3 - ls};
        floatx4 hi = {v4 - ls, v5 - ls, v6 - ls, v7 - ls};
        __builtin_nontemporal_store(lo, reinterpret_cast<floatx4*>(ro));
        __builtin_nontemporal_store(hi, reinterpret_cast<floatx4*>(ro) + 1);
    }
}

// ---------------------------------------------------------------------------
extern "C" void kernel_launch(void* const* d_in, const int* in_sizes, int n_in,
                              void* d_out, int out_size, void* d_ws, size_t ws_size,
                              hipStream_t stream) {
    const float* feature = (const float*)d_in[0];   // [N, 128]
    const float* weight  = (const float*)d_in[1];   // [40, 128]
    const float* bias    = (const float*)d_in[2];   // [40]
    const int*   ei      = (const int*)d_in[3];     // [2, E] (int32 or int64 words)
    const int N = N_NODES;
    const int E = in_sizes[3] / 2;

    size_t off = 0;
    auto take = [&](size_t bytes) { size_t o = off; off += (bytes + 255) & ~(size_t)255; return o; };
    char* ws = (char*)d_ws;
    int*   bCount    = (int*)  (ws + take((size_t)NBALLOC * 4));
    int*   starts    = (int*)  (ws + take((size_t)(N + 1) * 4));
    int*   mid1      = (int*)  (ws + take((size_t)N * 4));
    int*   mid2      = (int*)  (ws + take((size_t)N * 4));
    int*   mid3      = (int*)  (ws + take((size_t)N * 4));
    float* dis       = (float*)(ws + take((size_t)N * 4));
    int*   srcsB     = (int*)  (ws + take((size_t)E * 4));
    // t0+t1 (16 MB contiguous) also host tmp (per-bucket record regions,
    // NBUSED*CAP*4 = 13.6 MB; tmp dead once p4 finishes, before transform)
    unsigned short* t0 = (unsigned short*)(ws + take((size_t)N * N_CLASS * 2));
    unsigned short* t1 = (unsigned short*)(ws + take((size_t)N * N_CLASS * 2));
    unsigned int* tmp = (unsigned int*)t0;

    // --- build CSR (single-level fine bucketed counting sort) ---
    hipMemsetAsync(bCount, 0, (size_t)NBALLOC * 4, stream);
    const int p3grid = (E + P3BLK - 1) / P3BLK;
    p3a_scatter<<<p3grid, P3THR, 0, stream>>>(ei, E, bCount, tmp);
    p4_sort<<<NBUSED, 256, 0, stream>>>(tmp, bCount, starts, mid1, mid2, mid3,
                                        dis, srcsB, N, E);

    // --- transform (MFMA, pre-scaled f16 rows) then 2 merged-quarter hops ---
    const int ntile = (N + 15) / 16;
    const int tblocks = (ntile * 64 + 255) / 256;
    transform_mfma<<<tblocks, 256, 0, stream>>>(feature, weight, dis, t0, N);
    const int nwaves = (N + 11) / 12;                     // 12 nodes per wave
    const int nodeBlocks = (nwaves * 64 + 255) / 256;
    prop_hop<<<nodeBlocks, 256, 0, stream>>>(t0, t1, starts, mid1, mid2, mid3,
                                             srcsB, dis, N);
    prop_fin<<<nodeBlocks, 256, 0, stream>>>(t1, (float*)d_out, starts, mid1, mid2,
                                             mid3, srcsB, dis, bias, N);
}

// Round 16
// 267.513 us; speedup vs baseline: 1.0681x; 1.0681x over previous
//
#include <hip/hip_runtime.h>
#include <hip/hip_bf16.h>
#include <hip/hip_fp16.h>
#include <math.h>

// SGC: out = log_softmax( S^2 X W^T + b ), S = D^-1/2 (A+I) D^-1/2
// t0 = dis .* (X W^T) in *f16* (pre-scaled 80 B rows).
// Props (round 16): r14's TWO-range merged hops (best measured: 267 us)
// + r15's quarter ORDERING folded into p4 (1024-key sort). r15 proved
// finer windows cut FETCH (97->73 MB) but its 4-range loop overhead cost
// more than the bytes saved (+7 us, VALU 27->32%). Here edges within each
// half-segment are quarter-ordered, so the 2 MB sub-window locality comes
// for free: the gather loop is byte-identical to r14 (two ranges only).
// Gather: 5-lane group per dst, 12 nodes/wave, f32 accum, 8 edges in flight.
// r10 lesson: NO nontemporal on re-read data; only fin final store NT.
// CSR build: r7 LDS counting sort + r14's 512-thread p3a; r11 folds
// (is64 in p3a, p2 scan in p4). 6 dispatches total.

#define N_NODES 100000
#define N_FEAT  128
#define N_CLASS 40

#define RANGE   256           // dsts per fine bucket (pow2: dst>>8)
#define NBALLOC 512
#define NBUSED  391           // ceil(100000/256)
#define CAP     8704          // fine bucket cap (mean 8192 + ~5.7 sigma)
#define P3BLK   6250          // edges per p3a block (grid = ceil(E/P3BLK))
#define P3THR   512           // p3a threads per block (r14, proven)
#define Q1      25000         // quarter boundaries (2 MB table sub-windows)
#define Q2      50000         // Q2 is also the half boundary (mid)
#define Q3      75000

typedef __attribute__((ext_vector_type(8))) short short8;   // 8 bf16 (4 VGPRs)
typedef __attribute__((ext_vector_type(4))) float floatx4;  // f32x4 (NT-able)

__device__ __forceinline__ int edge_word(const int* ei, int elem, int is64) {
    return is64 ? ei[2 * elem] : ei[elem];
}
__device__ __forceinline__ int quarter_of(int src) {
    return (src >= Q1) + (src >= Q2) + (src >= Q3);
}

// P3a: per-block is64 detect, block-local LDS counting sort over 512 fine
// buckets, coalesced bucket-grouped run writes into tmp[f*CAP + p].
// bucketCount (pre-zeroed by memset) accumulates global per-bucket totals.
__global__ __launch_bounds__(P3THR) void p3a_scatter(
    const int* __restrict__ ei, int E,
    int* __restrict__ bucketCount, unsigned int* __restrict__ tmp)
{
    __shared__ unsigned int srt[P3BLK];     // bucket-grouped records
    __shared__ unsigned short fb[P3BLK];    // bucket id per record
    __shared__ int hist[NBALLOC];
    __shared__ int lbase[NBALLOC];          // block-local exclusive scan
    __shared__ int gbase[NBALLOC];          // global run base per bucket
    __shared__ int cur[NBALLOC];
    __shared__ int sc[NBALLOC];
    __shared__ int s_is64;
    int t = threadIdx.x;
    if (t < NBALLOC) hist[t] = 0;
    if (t < 64) {                            // wave 0: int32/int64 detect
        int nz = (ei[2 * t + 1] != 0) ? 1 : 0;
        unsigned long long bl = __ballot(nz);
        if (t == 0) s_is64 = (bl == 0ull) ? 1 : 0;
    }
    __syncthreads();
    int is64 = s_is64;
    int per = (E + gridDim.x - 1) / gridDim.x;
    int e0 = blockIdx.x * per;
    int e1 = min(E, e0 + per);
    int n = e1 - e0;
    for (int e = e0 + t; e < e1; e += P3THR) {
        int c = edge_word(ei, E + e, is64);
        atomicAdd(&hist[c >> 8], 1);
    }
    __syncthreads();
    int hv = hist[t];
    sc[t] = hv;
    __syncthreads();
    for (int o = 1; o < NBALLOC; o <<= 1) {
        int y = (t >= o) ? sc[t - o] : 0;
        __syncthreads();
        sc[t] += y;
        __syncthreads();
    }
    int excl = sc[t] - hv;
    lbase[t] = excl;
    cur[t] = excl;
    gbase[t] = hv ? atomicAdd(&bucketCount[t], hv) : 0;
    __syncthreads();
    for (int e = e0 + t; e < e1; e += P3THR) {
        int c = edge_word(ei, E + e, is64);
        int r = edge_word(ei, e, is64);
        int f = c >> 8;
        int p = atomicAdd(&cur[f], 1);
        srt[p] = ((unsigned)(c & 255) << 24) | (unsigned)r;
        fb[p] = (unsigned short)f;
    }
    __syncthreads();
    for (int i = t; i < n; i += P3THR) {
        int f = fb[i];
        int p = gbase[f] + (i - lbase[f]);
        if (p < CAP) tmp[(size_t)f * CAP + p] = srt[i];
    }
}

// P4: folded p2 scan of bucketCount -> block base; then per-fine-bucket LDS
// counting sort with 1024 keys (dlf*4 + srcQuarter) -> starts, mid (= half
// boundary, end of quarter1), dis, srcsB (byte offsets, src*80, coalesced).
// Quarter ordering within each half-segment is a free locality win for the
// hops' two-range gather. tmp[b*CAP + i] records (region-stride).
__global__ __launch_bounds__(256) void p4_sort(
    const unsigned int* __restrict__ tmp, const int* __restrict__ bucketCount,
    int* __restrict__ starts, int* __restrict__ mid, float* __restrict__ dis,
    int* __restrict__ srcsB, int N, int E)
{
    __shared__ int srt[CAP];
    __shared__ int hist[1024];
    __shared__ int sc[256];
    __shared__ int cur[1024];
    __shared__ int cnt[NBALLOC];
    __shared__ int base_s;
    int b = blockIdx.x, t = threadIdx.x;
    int g0 = b * RANGE;
    int gcnt = N - g0;
    if (gcnt > RANGE) gcnt = RANGE;
    // --- folded p2: scan the 512 global bucket counts for this block's base
    for (int i = t; i < NBALLOC; i += 256) cnt[i] = bucketCount[i];
    __syncthreads();
    int p0 = cnt[2 * t], p1 = cnt[2 * t + 1];
    sc[t] = p0 + p1;
    __syncthreads();
    for (int o = 1; o < 256; o <<= 1) {
        int y = (t >= o) ? sc[t - o] : 0;
        __syncthreads();
        sc[t] += y;
        __syncthreads();
    }
    if (t == 0) {
        int pairs = b >> 1;
        int base = (pairs > 0) ? sc[pairs - 1] : 0;
        if (b & 1) base += cnt[b - 1];
        base_s = base;
        if (b == 0) starts[N_NODES] = E;
    }
    __syncthreads();
    int base = base_s;
    int n = cnt[b];
    int nr = min(n, CAP);                       // records actually present
    const unsigned int* rec = tmp + (size_t)b * CAP;
    hist[t] = 0; hist[t + 256] = 0; hist[t + 512] = 0; hist[t + 768] = 0;
    __syncthreads();
    for (int i = t; i < nr; i += 256) {
        unsigned v = rec[i];
        int key = (int)((v >> 24) << 2) | quarter_of((int)(v & 0xFFFFFFu));
        atomicAdd(&hist[key], 1);
    }
    __syncthreads();
    int c0 = hist[4 * t], c1 = hist[4 * t + 1];
    int c2 = hist[4 * t + 2], c3 = hist[4 * t + 3];
    int tot = c0 + c1 + c2 + c3;
    sc[t] = tot;
    __syncthreads();
    for (int o = 1; o < 256; o <<= 1) {
        int y = (t >= o) ? sc[t - o] : 0;
        __syncthreads();
        sc[t] += y;
        __syncthreads();
    }
    int excl = sc[t] - tot;
    if (t < gcnt) {
        starts[g0 + t] = base + excl;
        mid[g0 + t] = base + excl + c0 + c1;      // half boundary (src < Q2)
        dis[g0 + t] = rsqrtf((float)(tot + 1));   // +1 self-loop
    }
    cur[4 * t] = excl;
    cur[4 * t + 1] = excl + c0;
    cur[4 * t + 2] = excl + c0 + c1;
    cur[4 * t + 3] = excl + c0 + c1 + c2;
    __syncthreads();
    for (int i = t; i < nr; i += 256) {
        unsigned v = rec[i];
        int src = (int)(v & 0xFFFFFFu);
        int key = (int)((v >> 24) << 2) | quarter_of(src);
        int p = atomicAdd(&cur[key], 1);
        srt[p] = src * 80;                       // pre-scaled byte offset
    }
    __syncthreads();
    for (int i = t; i < nr; i += 256) srcsB[base + i] = srt[i];
}

// ---------------------------------------------------------------------------
__device__ __forceinline__ unsigned short f2bf(float f) {   // RTN f32 -> bf16
    unsigned u = __float_as_uint(f);
    unsigned r = u + 0x7FFFu + ((u >> 16) & 1u);
    return (unsigned short)(r >> 16);
}
__device__ __forceinline__ __half2 u2h(unsigned w) {
    union { unsigned u; __half2 h; } c; c.u = w; return c.h;
}
__device__ __forceinline__ unsigned h2u(__half2 h) {
    union { unsigned u; __half2 h; } c; c.h = h; return c.u;
}

// t0 = dis .* (X @ W^T), f16, row stride 40 (80 B). One wave per 16 nodes.
// MFMA on bf16 inputs (f32 accumulate), output stored f16.
__global__ __launch_bounds__(256) void transform_mfma(
    const float* __restrict__ x, const float* __restrict__ W,
    const float* __restrict__ dis, unsigned short* __restrict__ t0, int N)
{
    __shared__ uint4 Wl[3 * 4 * 64];        // B frags, bf16-packed: 12 KiB
    int t = threadIdx.x;
    for (int i = t; i < 3 * 4 * 64; i += 256) {
        int lane = i & 63;
        int kc = (i >> 6) & 3;
        int nt = i >> 8;
        int n = nt * 16 + (lane & 15);
        int k = kc * 32 + (lane >> 4) * 8;
        union { unsigned short s[8]; uint4 v; } u;
        #pragma unroll
        for (int j = 0; j < 8; ++j)
            u.s[j] = (n < N_CLASS) ? f2bf(W[n * N_FEAT + k + j]) : (unsigned short)0;
        Wl[i] = u.v;
    }
    __syncthreads();
    int wave = (blockIdx.x * blockDim.x + threadIdx.x) >> 6;
    int lane = threadIdx.x & 63;
    int ntile = (N + 15) / 16;
    if (wave >= ntile) return;
    int m = lane & 15, quad = lane >> 4;
    int row = wave * 16 + m;
    const short8* Wf = reinterpret_cast<const short8*>(Wl);
    floatx4 acc0 = {0.f, 0.f, 0.f, 0.f}, acc1 = acc0, acc2 = acc0;
    #pragma unroll
    for (int kc = 0; kc < 4; ++kc) {
        const float4* xr = reinterpret_cast<const float4*>(
            x + (size_t)row * N_FEAT + kc * 32 + quad * 8);
        float4 a0 = xr[0], a1 = xr[1];
        short8 af;
        af[0] = f2bf(a0.x); af[1] = f2bf(a0.y); af[2] = f2bf(a0.z); af[3] = f2bf(a0.w);
        af[4] = f2bf(a1.x); af[5] = f2bf(a1.y); af[6] = f2bf(a1.z); af[7] = f2bf(a1.w);
        short8 b0 = Wf[(0 * 4 + kc) * 64 + lane];
        short8 b1 = Wf[(1 * 4 + kc) * 64 + lane];
        short8 b2 = Wf[(2 * 4 + kc) * 64 + lane];
        acc0 = __builtin_amdgcn_mfma_f32_16x16x32_bf16(af, b0, acc0, 0, 0, 0);
        acc1 = __builtin_amdgcn_mfma_f32_16x16x32_bf16(af, b1, acc1, 0, 0, 0);
        acc2 = __builtin_amdgcn_mfma_f32_16x16x32_bf16(af, b2, acc2, 0, 0, 0);
    }
    #pragma unroll
    for (int r = 0; r < 4; ++r) {
        int rw = wave * 16 + quad * 4 + r;
        float ds = dis[rw];
        unsigned short* tr = t0 + (size_t)rw * N_CLASS;
        tr[m] = __half_as_ushort(__float2half(ds * acc0[r]));
        tr[16 + m] = __half_as_ushort(__float2half(ds * acc1[r]));
        if (m < 8) tr[32 + m] = __half_as_ushort(__float2half(ds * acc2[r]));
    }
}

// ---------------------------------------------------------------------------
// Group-per-node gather: 12 groups x 5 lanes per wave; lane sl owns bytes
// [16*sl, 16*sl+16) of the 80 B row. f32 accumulation in two banks.
struct F8 { float v0, v1, v2, v3, v4, v5, v6, v7; };

__device__ __forceinline__ void acc8(F8& a, uint4 r) {
    float2 f0 = __half22float2(u2h(r.x));
    float2 f1 = __half22float2(u2h(r.y));
    float2 f2 = __half22float2(u2h(r.z));
    float2 f3 = __half22float2(u2h(r.w));
    a.v0 += f0.x; a.v1 += f0.y; a.v2 += f1.x; a.v3 += f1.y;
    a.v4 += f2.x; a.v5 += f2.y; a.v6 += f3.x; a.v7 += f3.y;
}

// Gather one edge range [e0, e1): 8 edges in flight, A/B bank alternation.
__device__ __forceinline__ void gather_range(
    const char* tbs, const int* __restrict__ srcsB, int e0, int e1,
    F8& A, F8& B)
{
    int e = e0;
    int ea = min(e1, (e0 + 3) & ~3);
    for (; e < ea; ++e) {                       // align to 16 B
        unsigned o = (unsigned)srcsB[e];
        uint4 r = *reinterpret_cast<const uint4*>(tbs + o);
        acc8(A, r);
    }
    for (; e + 8 <= e1; e += 8) {               // 8 gathers in flight
        int4 oa = *reinterpret_cast<const int4*>(srcsB + e);
        int4 ob = *reinterpret_cast<const int4*>(srcsB + e + 4);
        uint4 r0 = *reinterpret_cast<const uint4*>(tbs + (unsigned)oa.x);
        uint4 r1 = *reinterpret_cast<const uint4*>(tbs + (unsigned)oa.y);
        uint4 r2 = *reinterpret_cast<const uint4*>(tbs + (unsigned)oa.z);
        uint4 r3 = *reinterpret_cast<const uint4*>(tbs + (unsigned)oa.w);
        uint4 r4 = *reinterpret_cast<const uint4*>(tbs + (unsigned)ob.x);
        uint4 r5 = *reinterpret_cast<const uint4*>(tbs + (unsigned)ob.y);
        uint4 r6 = *reinterpret_cast<const uint4*>(tbs + (unsigned)ob.z);
        uint4 r7 = *reinterpret_cast<const uint4*>(tbs + (unsigned)ob.w);
        acc8(A, r0); acc8(B, r1); acc8(A, r2); acc8(B, r3);
        acc8(A, r4); acc8(B, r5); acc8(A, r6); acc8(B, r7);
    }
    for (; e + 4 <= e1; e += 4) {               // 4-wide remainder
        int4 o4 = *reinterpret_cast<const int4*>(srcsB + e);
        uint4 r0 = *reinterpret_cast<const uint4*>(tbs + (unsigned)o4.x);
        uint4 r1 = *reinterpret_cast<const uint4*>(tbs + (unsigned)o4.y);
        uint4 r2 = *reinterpret_cast<const uint4*>(tbs + (unsigned)o4.z);
        uint4 r3 = *reinterpret_cast<const uint4*>(tbs + (unsigned)o4.w);
        acc8(A, r0); acc8(B, r1); acc8(A, r2); acc8(B, r3);
    }
    for (; e < e1; ++e) {                       // tail <= 3 edges
        unsigned o = (unsigned)srcsB[e];
        uint4 r = *reinterpret_cast<const uint4*>(tbs + o);
        acc8(A, r);
    }
}

// Shared prologue + merged two-half gather (edges quarter-ordered within
// each half by p4). Self term added in the half containing d.
#define GATHER_BOTH(tin)                                                       \
    int wv = (blockIdx.x * blockDim.x + threadIdx.x) >> 6;                     \
    int lane = threadIdx.x & 63;                                               \
    int g = lane / 5;                                                          \
    int sl = lane - g * 5;                                                     \
    if (g > 11) { g = 11; sl = 0; }                                            \
    int d = wv * 12 + g;                                                       \
    int act = (lane < 60) && (d < N);                                          \
    int dc = min(d, N - 1);                                                    \
    int e0 = starts[dc];                                                       \
    int m  = mid[dc];                                                          \
    int e1 = starts[dc + 1];                                                   \
    if (d >= N) { m = e0; e1 = e0; }                                           \
    int slo = sl << 4;                                                         \
    const char* tbs = (const char*)(tin) + slo;                                \
    F8 A = {0,0,0,0,0,0,0,0}, B = {0,0,0,0,0,0,0,0};                           \
    if (dc < Q2) {                              /* self in half0 phase */      \
        uint4 rs = *reinterpret_cast<const uint4*>(tbs + (size_t)dc * 80);     \
        acc8(A, rs);                                                           \
    }                                                                          \
    gather_range(tbs, srcsB, e0, m, A, B);      /* half0 edges */              \
    if (dc >= Q2) {                             /* self in half1 phase */      \
        uint4 rs = *reinterpret_cast<const uint4*>(tbs + (size_t)dc * 80);     \
        acc8(A, rs);                                                           \
    }                                                                          \
    gather_range(tbs, srcsB, m, e1, A, B);      /* half1 edges */              \
    A.v0 += B.v0; A.v1 += B.v1; A.v2 += B.v2; A.v3 += B.v3;                    \
    A.v4 += B.v4; A.v5 += B.v5; A.v6 += B.v6; A.v7 += B.v7;

// Middle hop (merged halves): tout[d] = f16( dd^2 * (t[d] + sum t[src]) ).
__global__ __launch_bounds__(256) void prop_hop(
    const unsigned short* __restrict__ tin, unsigned short* __restrict__ tout,
    const int* __restrict__ starts, const int* __restrict__ mid,
    const int* __restrict__ srcsB, const float* __restrict__ dis, int N)
{
    GATHER_BOTH(tin)
    if (act) {
        float dd = dis[dc];
        float sc = dd * dd;
        uint4 o;
        o.x = h2u(__floats2half2_rn(sc * A.v0, sc * A.v1));
        o.y = h2u(__floats2half2_rn(sc * A.v2, sc * A.v3));
        o.z = h2u(__floats2half2_rn(sc * A.v4, sc * A.v5));
        o.w = h2u(__floats2half2_rn(sc * A.v6, sc * A.v7));
        *reinterpret_cast<uint4*>((char*)tout + (size_t)d * 80 + slo) = o;
    }
}

// Final hop (merged halves) fused with bias + log_softmax. Softmax reduce =
// 4 rotate-shfls within the 5-lane group. Final stores NT (never re-read).
__global__ __launch_bounds__(256) void prop_fin(
    const unsigned short* __restrict__ tin, float* __restrict__ out,
    const int* __restrict__ starts, const int* __restrict__ mid,
    const int* __restrict__ srcsB, const float* __restrict__ dis,
    const float* __restrict__ bias, int N)
{
    GATHER_BOTH(tin)
    float dd = dis[dc];
    float4 blo = reinterpret_cast<const float4*>(bias)[sl * 2];       // sl<5
    float4 bhi = reinterpret_cast<const float4*>(bias)[sl * 2 + 1];
    float v0 = dd * A.v0 + blo.x, v1 = dd * A.v1 + blo.y;
    float v2 = dd * A.v2 + blo.z, v3 = dd * A.v3 + blo.w;
    float v4 = dd * A.v4 + bhi.x, v5 = dd * A.v5 + bhi.y;
    float v6 = dd * A.v6 + bhi.z, v7 = dd * A.v7 + bhi.w;
    float mx = fmaxf(fmaxf(fmaxf(v0, v1), fmaxf(v2, v3)),
                     fmaxf(fmaxf(v4, v5), fmaxf(v6, v7)));
    int rot = g * 5 + ((sl + 1 == 5) ? 0 : sl + 1);     // next lane in group
    float tmx = mx;
    #pragma unroll
    for (int k = 0; k < 4; ++k) { tmx = __shfl(tmx, rot); mx = fmaxf(mx, tmx); }
    float s = expf(v0 - mx) + expf(v1 - mx) + expf(v2 - mx) + expf(v3 - mx)
            + expf(v4 - mx) + expf(v5 - mx) + expf(v6 - mx) + expf(v7 - mx);
    float ts = s;
    #pragma unroll
    for (int k = 0; k < 4; ++k) { ts = __shfl(ts, rot); s += ts; }
    if (act) {
        float ls = mx + logf(s);
        float* ro = out + (size_t)d * N_CLASS + sl * 8;
        floatx4 lo = {v0 - ls, v1 - ls, v2 - ls, v3 - ls};
        floatx4 hi = {v4 - ls, v5 - ls, v6 - ls, v7 - ls};
        __builtin_nontemporal_store(lo, reinterpret_cast<floatx4*>(ro));
        __builtin_nontemporal_store(hi, reinterpret_cast<floatx4*>(ro) + 1);
    }
}

// ---------------------------------------------------------------------------
extern "C" void kernel_launch(void* const* d_in, const int* in_sizes, int n_in,
                              void* d_out, int out_size, void* d_ws, size_t ws_size,
                              hipStream_t stream) {
    const float* feature = (const float*)d_in[0];   // [N, 128]
    const float* weight  = (const float*)d_in[1];   // [40, 128]
    const float* bias    = (const float*)d_in[2];   // [40]
    const int*   ei      = (const int*)d_in[3];     // [2, E] (int32 or int64 words)
    const int N = N_NODES;
    const int E = in_sizes[3] / 2;

    size_t off = 0;
    auto take = [&](size_t bytes) { size_t o = off; off += (bytes + 255) & ~(size_t)255; return o; };
    char* ws = (char*)d_ws;
    int*   bCount    = (int*)  (ws + take((size_t)NBALLOC * 4));
    int*   starts    = (int*)  (ws + take((size_t)(N + 1) * 4));
    int*   mid       = (int*)  (ws + take((size_t)N * 4));
    float* dis       = (float*)(ws + take((size_t)N * 4));
    int*   srcsB     = (int*)  (ws + take((size_t)E * 4));
    // t0+t1 (16 MB contiguous) also host tmp (per-bucket record regions,
    // NBUSED*CAP*4 = 13.6 MB; tmp dead once p4 finishes, before transform)
    unsigned short* t0 = (unsigned short*)(ws + take((size_t)N * N_CLASS * 2));
    unsigned short* t1 = (unsigned short*)(ws + take((size_t)N * N_CLASS * 2));
    unsigned int* tmp = (unsigned int*)t0;

    // --- build CSR (single-level fine bucketed counting sort) ---
    hipMemsetAsync(bCount, 0, (size_t)NBALLOC * 4, stream);
    const int p3grid = (E + P3BLK - 1) / P3BLK;
    p3a_scatter<<<p3grid, P3THR, 0, stream>>>(ei, E, bCount, tmp);
    p4_sort<<<NBUSED, 256, 0, stream>>>(tmp, bCount, starts, mid, dis, srcsB, N, E);

    // --- transform (MFMA, pre-scaled f16 rows) then 2 merged-half hops ---
    const int ntile = (N + 15) / 16;
    const int tblocks = (ntile * 64 + 255) / 256;
    transform_mfma<<<tblocks, 256, 0, stream>>>(feature, weight, dis, t0, N);
    const int nwaves = (N + 11) / 12;                     // 12 nodes per wave
    const int nodeBlocks = (nwaves * 64 + 255) / 256;
    prop_hop<<<nodeBlocks, 256, 0, stream>>>(t0, t1, starts, mid, srcsB, dis, N);
    prop_fin<<<nodeBlocks, 256, 0, stream>>>(t1, (float*)d_out, starts, mid, srcsB,
                                             dis, bias, N);
}